// Round 8
// baseline (267.808 us; speedup 1.0000x reference)
//
#include <hip/hip_runtime.h>
#include <hip/hip_fp16.h>

#define LL 2048
#define BB 2
#define DD 1024
#define HH 16
#define DKK 64

typedef _Float16 h8 __attribute__((ext_vector_type(8)));
typedef float f4 __attribute__((ext_vector_type(4)));
typedef float f16v __attribute__((ext_vector_type(16)));
typedef unsigned u2 __attribute__((ext_vector_type(2)));

// lgkm-only barrier (keeps in-flight global loads alive across it)
#define BAR() do {                                              \
    asm volatile("s_waitcnt lgkmcnt(0)" ::: "memory");          \
    __builtin_amdgcn_s_barrier();                               \
    asm volatile("" ::: "memory");                              \
} while (0)

// async global->LDS, 16B per lane; LDS dest is wave-uniform base + lane*16
__device__ __forceinline__ void gload_lds16(const void* g, void* l) {
    __builtin_amdgcn_global_load_lds(
        (const __attribute__((address_space(1))) void*)g,
        (__attribute__((address_space(3))) void*)l, 16, 0, 0);
}

// single v_cvt_pkrtz_f16_f32
__device__ __forceinline__ unsigned pack2h(float a, float b) {
    union { __fp16 v __attribute__((ext_vector_type(2))); unsigned u; } x;
    x.v = __builtin_amdgcn_cvt_pkrtz(a, b);
    return x.u;
}

// fragment-swizzled Q/K global layout:
//   [head][sch=l>>5][kf=dk>>4][hi=(dk>>3)&1][rq=l&31][j=dk&7]
__device__ __forceinline__ size_t swz(int head, int l, int dk) {
    return ((((size_t)(head * 64 + (l >> 5)) * 4 + (dk >> 4)) * 2 +
             ((dk >> 3) & 1)) * 32 + (l & 31)) * 8 + (dk & 7);
}

// ---------------------------------------------------------------------------
// Kernel 0: convert the 4 weight matrices f32->f16 (1M elements each).
// ---------------------------------------------------------------------------
__global__ __launch_bounds__(256) void cvt_w(
    const float* __restrict__ w0, const float* __restrict__ w1,
    const float* __restrict__ w2, const float* __restrict__ w3,
    _Float16* __restrict__ z0, _Float16* __restrict__ z1,
    _Float16* __restrict__ z2, _Float16* __restrict__ z3)
{
    const int sel = blockIdx.y;
    const float* src = (sel == 0) ? w0 : (sel == 1) ? w1 : (sel == 2) ? w2 : w3;
    _Float16* dst = (sel == 0) ? z0 : (sel == 1) ? z1 : (sel == 2) ? z2 : z3;
    const int i = (blockIdx.x * 256 + threadIdx.x) * 8;
    f4 a = *(const f4*)(src + i);
    f4 b = *(const f4*)(src + i + 4);
    h8 o = {(_Float16)a.x, (_Float16)a.y, (_Float16)a.z, (_Float16)a.w,
            (_Float16)b.x, (_Float16)b.y, (_Float16)b.z, (_Float16)b.w};
    *(h8*)(dst + i) = o;
}

// ---------------------------------------------------------------------------
// Kernel 1: QKV projections. X is f32 (converted during A-staging, padded
// LDS); W is pre-converted f16 (gload_lds16, m97-style).
//   mode 0: Q -> swizzled qhf, * (0.125*log2e)
//   mode 1: K -> swizzled khf
//   mode 2: V -> vth[head][dk][l]
// ---------------------------------------------------------------------------
__global__ __launch_bounds__(256) void qkv_proj(
    const float* __restrict__ xq, const float* __restrict__ xk,
    const float* __restrict__ xv,
    const _Float16* __restrict__ wq, const float* __restrict__ bq,
    const _Float16* __restrict__ wk, const float* __restrict__ bk,
    const _Float16* __restrict__ wv, const float* __restrict__ bv,
    _Float16* __restrict__ qhf, _Float16* __restrict__ khf,
    _Float16* __restrict__ vth)
{
    const int mode = blockIdx.z;
    const float*    X    = (mode == 0) ? xq : (mode == 1) ? xk : xv;
    const _Float16* W    = (mode == 0) ? wq : (mode == 1) ? wk : wv;
    const float*    bias = (mode == 0) ? bq : (mode == 1) ? bk : bv;

    __shared__ alignas(16) _Float16 a_sm[128 * 40];  // padded (conflict-free)
    __shared__ alignas(16) _Float16 b_sm[128 * 32];  // m97 unpadded (gload)

    const int tid  = threadIdx.x;
    const int lane = tid & 63;
    const int wave = tid >> 6;
    const int wm = (wave & 1) * 64;
    const int wn = (wave >> 1) * 64;
    const int m0 = blockIdx.x * 128;
    const int n0 = blockIdx.y * 128;

    const int srowA = tid >> 3;        // 0..31
    const int scolA = (tid & 7) * 4;   // f32 quads
    const int srowB = tid >> 2;        // 0..63
    const int scolB = (tid & 3) * 8;
    const int ldsB  = wave * 512;

    f4 acc[4][4];
    #pragma unroll
    for (int i = 0; i < 4; i++)
        #pragma unroll
        for (int j = 0; j < 4; j++)
            #pragma unroll
            for (int r = 0; r < 4; r++) acc[i][j][r] = 0.f;

    const int fr = lane & 15;
    const int fk = (lane >> 4) * 8;

    for (int k0 = 0; k0 < DD; k0 += 32) {
        // B: async f16 staging
        gload_lds16(W + (size_t)(n0 + srowB) * DD + k0 + scolB,      &b_sm[ldsB]);
        gload_lds16(W + (size_t)(n0 + 64 + srowB) * DD + k0 + scolB, &b_sm[2048 + ldsB]);
        // A: register-stage f32 -> cvt -> padded LDS
        #pragma unroll
        for (int r = 0; r < 4; r++) {
            f4 va = *(const f4*)(X + (size_t)(m0 + srowA + 32 * r) * DD + k0 + scolA);
            u2 pk = {pack2h(va.x, va.y), pack2h(va.z, va.w)};
            *(u2*)&a_sm[(srowA + 32 * r) * 40 + scolA] = pk;
        }
        __syncthreads();
        h8 af[4], bfr[4];
        #pragma unroll
        for (int i = 0; i < 4; i++) af[i]  = *(const h8*)&a_sm[(wm + i * 16 + fr) * 40 + fk];
        #pragma unroll
        for (int j = 0; j < 4; j++) bfr[j] = *(const h8*)&b_sm[(wn + j * 16 + fr) * 32 + fk];
        #pragma unroll
        for (int i = 0; i < 4; i++)
            #pragma unroll
            for (int j = 0; j < 4; j++)
                acc[i][j] = __builtin_amdgcn_mfma_f32_16x16x32_f16(af[i], bfr[j], acc[i][j], 0, 0, 0);
        __syncthreads();
    }

    const int colc = lane & 15;
    const int rowb = (lane >> 4) * 4;
    #pragma unroll
    for (int i = 0; i < 4; i++) {
        #pragma unroll
        for (int j = 0; j < 4; j++) {
            const int nn = n0 + wn + j * 16 + colc;
            const float bval = bias[nn];
            #pragma unroll
            for (int reg = 0; reg < 4; reg++) {
                const int mm = m0 + wm + i * 16 + rowb + reg;
                float v = acc[i][j][reg] + bval;
                const int b = mm & 1, l = mm >> 1;
                const int h = nn >> 6, dk = nn & 63;
                const int head = b * HH + h;
                if (mode == 0) {
                    v *= 0.1803368801111243f;  // DK^-0.5 * log2(e)
                    qhf[swz(head, l, dk)] = (_Float16)v;
                } else if (mode == 1) {
                    khf[swz(head, l, dk)] = (_Float16)v;
                } else {
                    vth[((size_t)head * DKK + dk) * LL + l] = (_Float16)v;
                }
            }
        }
    }
}

// ---------------------------------------------------------------------------
// Kernel 2: attention v5.
// Block = (64 q, head); wave = (q-strip = wave&1, s-half = wave>>1).
// K/Q fragments loaded DIRECTLY from swizzled global (coalesced dwordx4; no
// K LDS at all).  V^T in LDS with ping-pong double-buffer -> ONE barrier per
// 128-s superstep.  Scores transposed (S^T = K.Q^T); P built in-register via
// targeted 4-shfl half-wave exchange.  Per-lane lsum; epilogue combines the
// two s-halves through LDS overlay.
// ---------------------------------------------------------------------------
__global__ __launch_bounds__(256, 3) void attn(
    const _Float16* __restrict__ qhf, const _Float16* __restrict__ khf,
    const _Float16* __restrict__ vth, _Float16* __restrict__ oh)
{
    const int head = blockIdx.y;
    const int q0   = blockIdx.x * 64;
    const int tid = threadIdx.x, lane = tid & 63, wave = tid >> 6;
    const int qs = wave & 1;
    const int sw = wave >> 1;
    const int qw = q0 + qs * 32;

    // vtsm: [p][b2][64 dk][72] halves = 36864 B; tail 512 B: lsp/invp.
    // epilogue overlay: comb [2][32][64] f32 = 16384 B at offset 0 (buffer p=0,
    // last read at it=14, two barriers before overlay use).
    __shared__ alignas(16) char smem[37376];
    _Float16* vtsm = (_Float16*)smem;

    const int rq = lane & 31;
    const int hi = lane >> 5;
    const int tid8 = tid * 8;

    const _Float16* vthead = vth + (size_t)head * DKK * LL;

    // Q B-frags (swizzled global, coalesced): B[n=q=rq][k=hi*8+j]
    const _Float16* qbase = qhf + (size_t)(head * 64 + (qw >> 5)) * 2048;
    h8 qa[4];
    #pragma unroll
    for (int kf = 0; kf < 4; kf++)
        qa[kf] = *(const h8*)(qbase + kf * 512 + hi * 256 + rq * 8);

    const _Float16* kbase0 = khf + (size_t)(head * 64) * 2048;

    f16v o0, o1;
    #pragma unroll
    for (int r = 0; r < 16; r++) { o0[r] = 0.f; o1[r] = 0.f; }
    float lsum = 0.f;

    // stage superstep 0 into buffer p=0
    #pragma unroll
    for (int b2 = 0; b2 < 2; b2++)
        #pragma unroll
        for (int i = 0; i < 2; i++) {
            const int flat = i * 2048 + tid8;
            const int row = flat >> 6, col = flat & 63;
            *(h8*)&vtsm[b2 * 4608 + row * 72 + col] =
                *(const h8*)(vthead + (size_t)row * LL + b2 * 64 + col);
        }
    BAR();

    for (int it = 0; it < 16; ++it) {
        const int p = it & 1;
        const int s1 = it * 128 + 128;
        const bool more = (s1 < LL);

        // K A-frags for this superstep: coalesced global (this wave's 64 s)
        const _Float16* kb = kbase0 + (size_t)(it * 4 + sw * 2) * 2048;
        h8 kc[2][4];
        #pragma unroll
        for (int st = 0; st < 2; st++)
            #pragma unroll
            for (int kf = 0; kf < 4; kf++)
                kc[st][kf] = *(const h8*)(kb + st * 2048 + kf * 512 + hi * 256 + rq * 8);

        // V prefetch for next superstep (registers)
        h8 vpre[4];
        if (more) {
            #pragma unroll
            for (int b2 = 0; b2 < 2; b2++)
                #pragma unroll
                for (int i = 0; i < 2; i++) {
                    const int flat = i * 2048 + tid8;
                    const int row = flat >> 6, col = flat & 63;
                    vpre[b2 * 2 + i] =
                        *(const h8*)(vthead + (size_t)row * LL + s1 + b2 * 64 + col);
                }
        }

        const _Float16* vb = vtsm + p * 9216 + sw * 4608;

        #pragma unroll
        for (int st = 0; st < 2; st++) {
            f16v sc;
            #pragma unroll
            for (int r = 0; r < 16; r++) sc[r] = 0.f;
            #pragma unroll
            for (int kf = 0; kf < 4; kf++)
                sc = __builtin_amdgcn_mfma_f32_32x32x16_f16(kc[st][kf], qa[kf], sc, 0, 0, 0);

            float pr[16];
            #pragma unroll
            for (int r = 0; r < 16; r++) {
                pr[r] = __builtin_amdgcn_exp2f(sc[r]);
                lsum += pr[r];
            }
            unsigned own[4][2];
            #pragma unroll
            for (int g = 0; g < 4; g++) {
                own[g][0] = pack2h(pr[4 * g],     pr[4 * g + 1]);
                own[g][1] = pack2h(pr[4 * g + 2], pr[4 * g + 3]);
            }
            // targeted exchange: hi=0 needs partner g0,g2; hi=1 needs g1,g3
            unsigned X0 = hi ? own[0][0] : own[1][0];
            unsigned X1 = hi ? own[0][1] : own[1][1];
            unsigned Y0 = hi ? own[2][0] : own[3][0];
            unsigned Y1 = hi ? own[2][1] : own[3][1];
            const unsigned rX0 = __shfl_xor(X0, 32, 64);
            const unsigned rX1 = __shfl_xor(X1, 32, 64);
            const unsigned rY0 = __shfl_xor(Y0, 32, 64);
            const unsigned rY1 = __shfl_xor(Y1, 32, 64);

            union { unsigned u[4]; h8 h; } pa0, pa1;
            pa0.u[0] = hi ? rX0 : own[0][0];
            pa0.u[1] = hi ? rX1 : own[0][1];
            pa0.u[2] = hi ? own[1][0] : rX0;
            pa0.u[3] = hi ? own[1][1] : rX1;
            pa1.u[0] = hi ? rY0 : own[2][0];
            pa1.u[1] = hi ? rY1 : own[2][1];
            pa1.u[2] = hi ? own[3][0] : rY0;
            pa1.u[3] = hi ? own[3][1] : rY1;

            const int vc0 = st * 32 + hi * 8;
            h8 b00 = *(const h8*)&vb[rq * 72 + vc0];
            h8 b10 = *(const h8*)&vb[(32 + rq) * 72 + vc0];
            o0 = __builtin_amdgcn_mfma_f32_32x32x16_f16(pa0.h, b00, o0, 0, 0, 0);
            o1 = __builtin_amdgcn_mfma_f32_32x32x16_f16(pa0.h, b10, o1, 0, 0, 0);
            h8 b01 = *(const h8*)&vb[rq * 72 + vc0 + 16];
            h8 b11 = *(const h8*)&vb[(32 + rq) * 72 + vc0 + 16];
            o0 = __builtin_amdgcn_mfma_f32_32x32x16_f16(pa1.h, b01, o0, 0, 0, 0);
            o1 = __builtin_amdgcn_mfma_f32_32x32x16_f16(pa1.h, b11, o1, 0, 0, 0);
        }

        // write prefetched V into the other buffer (its readers finished at
        // the barrier ending superstep it-1), then one barrier publishes it.
        if (more) {
            _Float16* wbuf = vtsm + (p ^ 1) * 9216;
            #pragma unroll
            for (int b2 = 0; b2 < 2; b2++)
                #pragma unroll
                for (int i = 0; i < 2; i++) {
                    const int flat = i * 2048 + tid8;
                    const int row = flat >> 6, col = flat & 63;
                    *(h8*)&wbuf[b2 * 4608 + row * 72 + col] = vpre[b2 * 2 + i];
                }
        }
        BAR();
    }

    // fold half-wave partner (hi split of s within this wave's chunk)
    lsum += __shfl_xor(lsum, 32, 64);

    // cross-pair combine: waves sw=1 hand off to sw=0 via LDS overlay
    float* comb = (float*)smem;                 // [2][32][64]
    float* lsp  = (float*)(smem + 36864);       // [2][32]
    float* invp = (float*)(smem + 37120);       // [2][32]

    if (wave >= 2) {
        float* c = comb + qs * 2048;
        #pragma unroll
        for (int r = 0; r < 16; r++) {
            const int row = (r & 3) + 8 * (r >> 2) + 4 * hi;
            c[row * 64 + rq]      = o0[r];
            c[row * 64 + 32 + rq] = o1[r];
        }
        if (hi == 0) lsp[qs * 32 + rq] = lsum;
    }
    BAR();
    if (wave < 2) {
        lsum += lsp[qs * 32 + rq];
        invp[qs * 32 + rq] = 1.0f / lsum;       // hi halves write same value
        asm volatile("s_waitcnt lgkmcnt(0)" ::: "memory");
        const int b = head >> 4, h = head & 15;
        const float* c = comb + qs * 2048;
        #pragma unroll
        for (int r = 0; r < 16; r++) {
            const int row = (r & 3) + 8 * (r >> 2) + 4 * hi;
            const float inv = invp[qs * 32 + row];
            const int ql = qw + row;
            const size_t base = (size_t)(ql * BB + b) * DD + h * DKK;
            oh[base + rq]      = (_Float16)((o0[r] + c[row * 64 + rq]) * inv);
            oh[base + 32 + rq] = (_Float16)((o1[r] + c[row * 64 + 32 + rq]) * inv);
        }
    }
}

// ---------------------------------------------------------------------------
// Kernel 3: output projection, m97 structure, 64x128 tiles (grid 512).
// ---------------------------------------------------------------------------
__global__ __launch_bounds__(256) void out_proj(
    const _Float16* __restrict__ oh, const _Float16* __restrict__ wo,
    const float* __restrict__ bo, float* __restrict__ out)
{
    __shared__ alignas(16) _Float16 a_sm[64 * 32];
    __shared__ alignas(16) _Float16 b_sm[128 * 32];
    const int tid = threadIdx.x, lane = tid & 63, wave = tid >> 6;
    const int wm = (wave & 1) * 32, wn = (wave >> 1) * 64;
    const int m0 = blockIdx.x * 64, n0 = blockIdx.y * 128;

    const int srow = tid >> 2;
    const int scol = (tid & 3) * 8;
    const int lds_base = wave * 512;

    f4 acc[2][4];
    #pragma unroll
    for (int i = 0; i < 2; i++)
        #pragma unroll
        for (int j = 0; j < 4; j++)
            #pragma unroll
            for (int r = 0; r < 4; r++) acc[i][j][r] = 0.f;

    const int fr = lane & 15;
    const int fk = (lane >> 4) * 8;

    for (int k0 = 0; k0 < DD; k0 += 32) {
        gload_lds16(oh + (size_t)(m0 + srow) * DD + k0 + scol,      &a_sm[lds_base]);
        gload_lds16(wo + (size_t)(n0 + srow) * DD + k0 + scol,      &b_sm[lds_base]);
        gload_lds16(wo + (size_t)(n0 + 64 + srow) * DD + k0 + scol, &b_sm[2048 + lds_base]);
        __syncthreads();
        h8 af[2], bfr[4];
        #pragma unroll
        for (int i = 0; i < 2; i++) af[i]  = *(const h8*)&a_sm[(wm + i * 16 + fr) * 32 + fk];
        #pragma unroll
        for (int j = 0; j < 4; j++) bfr[j] = *(const h8*)&b_sm[(wn + j * 16 + fr) * 32 + fk];
        #pragma unroll
        for (int i = 0; i < 2; i++)
            #pragma unroll
            for (int j = 0; j < 4; j++)
                acc[i][j] = __builtin_amdgcn_mfma_f32_16x16x32_f16(af[i], bfr[j], acc[i][j], 0, 0, 0);
        __syncthreads();
    }

    const int colc = lane & 15;
    const int rowb = (lane >> 4) * 4;
    #pragma unroll
    for (int i = 0; i < 2; i++) {
        #pragma unroll
        for (int j = 0; j < 4; j++) {
            const int nn = n0 + wn + j * 16 + colc;
            const float bval = bo[nn];
            #pragma unroll
            for (int reg = 0; reg < 4; reg++) {
                const int mm = m0 + wm + i * 16 + rowb + reg;
                out[(size_t)mm * DD + nn] = acc[i][j][reg] + bval;
            }
        }
    }
}

extern "C" void kernel_launch(void* const* d_in, const int* in_sizes, int n_in,
                              void* d_out, int out_size, void* d_ws, size_t ws_size,
                              hipStream_t stream) {
    const float* qin = (const float*)d_in[0];
    const float* kin = (const float*)d_in[1];
    const float* vin = (const float*)d_in[2];
    const float* wq  = (const float*)d_in[3];
    const float* bq  = (const float*)d_in[4];
    const float* wk  = (const float*)d_in[5];
    const float* bk  = (const float*)d_in[6];
    const float* wv  = (const float*)d_in[7];
    const float* bv  = (const float*)d_in[8];
    const float* wo  = (const float*)d_in[9];
    const float* bo  = (const float*)d_in[10];

    // ws (halves): qhf,khf,vth,oh (4M each) | wqh,wkh,wvh,woh (1M each) = 40 MB
    const size_t seg = (size_t)32 * LL * DKK;  // 4,194,304 halves
    _Float16* qhf = (_Float16*)d_ws;
    _Float16* khf = qhf + seg;
    _Float16* vth = khf + seg;
    _Float16* oh  = vth + seg;
    _Float16* wqh = oh + seg;
    _Float16* wkh = wqh + (size_t)DD * DD;
    _Float16* wvh = wkh + (size_t)DD * DD;
    _Float16* woh = wvh + (size_t)DD * DD;

    hipLaunchKernelGGL(cvt_w, dim3(512, 4), dim3(256), 0, stream,
                       wq, wk, wv, wo, wqh, wkh, wvh, woh);
    hipLaunchKernelGGL(qkv_proj, dim3(32, 8, 3), dim3(256), 0, stream,
                       qin, kin, vin, wqh, bq, wkh, bk, wvh, bv, qhf, khf, vth);
    hipLaunchKernelGGL(attn, dim3(32, 32), dim3(256), 0, stream, qhf, khf, vth, oh);
    hipLaunchKernelGGL(out_proj, dim3(64, 8), dim3(256), 0, stream, oh, woh,
                       bo, (float*)d_out);
}

// Round 9
// 253.088 us; speedup vs baseline: 1.0582x; 1.0582x over previous
//
#include <hip/hip_runtime.h>
#include <hip/hip_fp16.h>

#define LL 2048
#define BB 2
#define DD 1024
#define HH 16
#define DKK 64

typedef _Float16 h8 __attribute__((ext_vector_type(8)));
typedef float f4 __attribute__((ext_vector_type(4)));
typedef float f16v __attribute__((ext_vector_type(16)));

// lgkm-only barrier (keeps in-flight global loads alive across it)
#define BAR() do {                                              \
    asm volatile("s_waitcnt lgkmcnt(0)" ::: "memory");          \
    __builtin_amdgcn_s_barrier();                               \
    asm volatile("" ::: "memory");                              \
} while (0)

// async global->LDS, 16B per lane; LDS dest is wave-uniform base + lane*16
__device__ __forceinline__ void gload_lds16(const void* g, void* l) {
    __builtin_amdgcn_global_load_lds(
        (const __attribute__((address_space(1))) void*)g,
        (__attribute__((address_space(3))) void*)l, 16, 0, 0);
}

// single v_cvt_pkrtz_f16_f32
__device__ __forceinline__ unsigned pack2h(float a, float b) {
    union { __fp16 v __attribute__((ext_vector_type(2))); unsigned u; } x;
    x.v = __builtin_amdgcn_cvt_pkrtz(a, b);
    return x.u;
}

// ---------------------------------------------------------------------------
// Kernel 0: convert 7 arrays f32->f16: qin/kin/vin (4M each), wq/wk/wv/wo (1M).
// ---------------------------------------------------------------------------
__global__ __launch_bounds__(256) void cvt_all(
    const float* __restrict__ x0, const float* __restrict__ x1,
    const float* __restrict__ x2, const float* __restrict__ w0,
    const float* __restrict__ w1, const float* __restrict__ w2,
    const float* __restrict__ w3,
    _Float16* __restrict__ y0, _Float16* __restrict__ y1,
    _Float16* __restrict__ y2, _Float16* __restrict__ z0,
    _Float16* __restrict__ z1, _Float16* __restrict__ z2,
    _Float16* __restrict__ z3)
{
    const int sel = blockIdx.y;
    if (sel >= 3 && blockIdx.x >= 512) return;
    const float* src = (sel == 0) ? x0 : (sel == 1) ? x1 : (sel == 2) ? x2
                     : (sel == 3) ? w0 : (sel == 4) ? w1 : (sel == 5) ? w2 : w3;
    _Float16* dst = (sel == 0) ? y0 : (sel == 1) ? y1 : (sel == 2) ? y2
                  : (sel == 3) ? z0 : (sel == 4) ? z1 : (sel == 5) ? z2 : z3;
    const int i = (blockIdx.x * 256 + threadIdx.x) * 8;
    f4 a = *(const f4*)(src + i);
    f4 b = *(const f4*)(src + i + 4);
    h8 o = {(_Float16)a.x, (_Float16)a.y, (_Float16)a.z, (_Float16)a.w,
            (_Float16)b.x, (_Float16)b.y, (_Float16)b.z, (_Float16)b.w};
    *(h8*)(dst + i) = o;
}

// ---------------------------------------------------------------------------
// Kernel 1: QKV projections, m97 structure (R7 config — known good).
//   mode 0: Q -> qh[head][l][dk] * (0.125 * log2e)   [attn uses exp2]
//   mode 1: K -> kh[head][l][dk]
//   mode 2: V -> vth[head][dk][l]
// ---------------------------------------------------------------------------
__global__ __launch_bounds__(256) void qkv_proj(
    const _Float16* __restrict__ xq, const _Float16* __restrict__ xk,
    const _Float16* __restrict__ xv,
    const _Float16* __restrict__ wq, const float* __restrict__ bq,
    const _Float16* __restrict__ wk, const float* __restrict__ bk,
    const _Float16* __restrict__ wv, const float* __restrict__ bv,
    _Float16* __restrict__ qh, _Float16* __restrict__ kh,
    _Float16* __restrict__ vth)
{
    const int mode = blockIdx.z;
    const _Float16* X    = (mode == 0) ? xq : (mode == 1) ? xk : xv;
    const _Float16* W    = (mode == 0) ? wq : (mode == 1) ? wk : wv;
    const float*    bias = (mode == 0) ? bq : (mode == 1) ? bk : bv;

    __shared__ alignas(16) _Float16 a_sm[128 * 32];
    __shared__ alignas(16) _Float16 b_sm[128 * 32];

    const int tid  = threadIdx.x;
    const int lane = tid & 63;
    const int wave = tid >> 6;
    const int wm = (wave & 1) * 64;
    const int wn = (wave >> 1) * 64;
    const int m0 = blockIdx.x * 128;
    const int n0 = blockIdx.y * 128;

    const int srow = tid >> 2;
    const int scol = (tid & 3) * 8;
    const int lds_base = wave * 512;

    f4 acc[4][4];
    #pragma unroll
    for (int i = 0; i < 4; i++)
        #pragma unroll
        for (int j = 0; j < 4; j++)
            #pragma unroll
            for (int r = 0; r < 4; r++) acc[i][j][r] = 0.f;

    const int fr = lane & 15;
    const int fk = (lane >> 4) * 8;

    for (int k0 = 0; k0 < DD; k0 += 32) {
        gload_lds16(X + (size_t)(m0 + srow) * DD + k0 + scol,       &a_sm[lds_base]);
        gload_lds16(X + (size_t)(m0 + 64 + srow) * DD + k0 + scol,  &a_sm[2048 + lds_base]);
        gload_lds16(W + (size_t)(n0 + srow) * DD + k0 + scol,       &b_sm[lds_base]);
        gload_lds16(W + (size_t)(n0 + 64 + srow) * DD + k0 + scol,  &b_sm[2048 + lds_base]);
        __syncthreads();
        h8 af[4], bfr[4];
        #pragma unroll
        for (int i = 0; i < 4; i++) af[i]  = *(const h8*)&a_sm[(wm + i * 16 + fr) * 32 + fk];
        #pragma unroll
        for (int j = 0; j < 4; j++) bfr[j] = *(const h8*)&b_sm[(wn + j * 16 + fr) * 32 + fk];
        #pragma unroll
        for (int i = 0; i < 4; i++)
            #pragma unroll
            for (int j = 0; j < 4; j++)
                acc[i][j] = __builtin_amdgcn_mfma_f32_16x16x32_f16(af[i], bfr[j], acc[i][j], 0, 0, 0);
        __syncthreads();
    }

    const int colc = lane & 15;
    const int rowb = (lane >> 4) * 4;
    #pragma unroll
    for (int i = 0; i < 4; i++) {
        #pragma unroll
        for (int j = 0; j < 4; j++) {
            const int nn = n0 + wn + j * 16 + colc;
            const float bval = bias[nn];
            #pragma unroll
            for (int reg = 0; reg < 4; reg++) {
                const int mm = m0 + wm + i * 16 + rowb + reg;
                float v = acc[i][j][reg] + bval;
                const int b = mm & 1, l = mm >> 1;
                const int h = nn >> 6, dk = nn & 63;
                const int head = b * HH + h;
                if (mode == 0) {
                    v *= 0.1803368801111243f;  // DK^-0.5 * log2(e)
                    qh[((size_t)head * LL + l) * DKK + dk] = (_Float16)v;
                } else if (mode == 1) {
                    kh[((size_t)head * LL + l) * DKK + dk] = (_Float16)v;
                } else {
                    vth[((size_t)head * DKK + dk) * LL + l] = (_Float16)v;
                }
            }
        }
    }
}

// ---------------------------------------------------------------------------
// Kernel 2: attention v6.
// Block = (64 q, head); wave = (q-strip = wave&1, s-half = wave>>1).
// K and Q fragments loaded DIRECTLY from the standard [head][l][dk] global
// layout (16B/lane strided gather, L2-resident; no K LDS at all), with K
// register-prefetch one superstep ahead.  V^T in LDS ping-pong -> ONE
// barrier per 128-s superstep.  Scores transposed (S^T = K.Q^T); P built
// in-register via targeted 4-shfl half-wave exchange (verified R8).
// ---------------------------------------------------------------------------
__global__ __launch_bounds__(256, 3) void attn(
    const _Float16* __restrict__ qh, const _Float16* __restrict__ kh,
    const _Float16* __restrict__ vth, _Float16* __restrict__ oh)
{
    const int head = blockIdx.y;
    const int q0   = blockIdx.x * 64;
    const int tid = threadIdx.x, lane = tid & 63, wave = tid >> 6;
    const int qs = wave & 1;
    const int sw = wave >> 1;
    const int qw = q0 + qs * 32;

    // vtsm: [p][b2][64 dk][72] halves = 36864 B; tail 512 B: lsp/invp.
    // epilogue overlay: comb [2][32][64] f32 = 16384 B at offset 0.
    __shared__ alignas(16) char smem[37376];
    _Float16* vtsm = (_Float16*)smem;

    const int rq = lane & 31;
    const int hi = lane >> 5;
    const int tid8 = tid * 8;

    const _Float16* khead  = kh  + (size_t)head * LL * DKK;
    const _Float16* vthead = vth + (size_t)head * DKK * LL;

    // Q B-frags: B[n=q=rq][k=kf*16+hi*8+j]
    const _Float16* qbase = qh + ((size_t)head * LL + qw + rq) * DKK;
    h8 qa[4];
    #pragma unroll
    for (int kf = 0; kf < 4; kf++)
        qa[kf] = *(const h8*)(qbase + kf * 16 + hi * 8);

    // K A-frags for superstep 0 (this wave's 64-s half): A[m=s][k=dk]
    h8 kc[2][4];
    #pragma unroll
    for (int st = 0; st < 2; st++)
        #pragma unroll
        for (int kf = 0; kf < 4; kf++)
            kc[st][kf] = *(const h8*)(khead +
                (size_t)(sw * 64 + st * 32 + rq) * DKK + kf * 16 + hi * 8);

    f16v o0, o1;
    #pragma unroll
    for (int r = 0; r < 16; r++) { o0[r] = 0.f; o1[r] = 0.f; }
    float lsum = 0.f;

    // stage V superstep 0 into buffer p=0
    #pragma unroll
    for (int b2 = 0; b2 < 2; b2++)
        #pragma unroll
        for (int i = 0; i < 2; i++) {
            const int flat = i * 2048 + tid8;
            const int row = flat >> 6, col = flat & 63;
            *(h8*)&vtsm[b2 * 4608 + row * 72 + col] =
                *(const h8*)(vthead + (size_t)row * LL + b2 * 64 + col);
        }
    BAR();

    for (int it = 0; it < 16; ++it) {
        const int p = it & 1;
        const int s1 = it * 128 + 128;
        const bool more = (s1 < LL);

        // prefetch next superstep's K frags + V chunk into registers
        h8 kpre[2][4], vpre[4];
        if (more) {
            #pragma unroll
            for (int st = 0; st < 2; st++)
                #pragma unroll
                for (int kf = 0; kf < 4; kf++)
                    kpre[st][kf] = *(const h8*)(khead +
                        (size_t)(s1 + sw * 64 + st * 32 + rq) * DKK + kf * 16 + hi * 8);
            #pragma unroll
            for (int b2 = 0; b2 < 2; b2++)
                #pragma unroll
                for (int i = 0; i < 2; i++) {
                    const int flat = i * 2048 + tid8;
                    const int row = flat >> 6, col = flat & 63;
                    vpre[b2 * 2 + i] =
                        *(const h8*)(vthead + (size_t)row * LL + s1 + b2 * 64 + col);
                }
        }

        const _Float16* vb = vtsm + p * 9216 + sw * 4608;

        #pragma unroll
        for (int st = 0; st < 2; st++) {
            f16v sc;
            #pragma unroll
            for (int r = 0; r < 16; r++) sc[r] = 0.f;
            #pragma unroll
            for (int kf = 0; kf < 4; kf++)
                sc = __builtin_amdgcn_mfma_f32_32x32x16_f16(kc[st][kf], qa[kf], sc, 0, 0, 0);

            float pr[16];
            #pragma unroll
            for (int r = 0; r < 16; r++) {
                pr[r] = __builtin_amdgcn_exp2f(sc[r]);
                lsum += pr[r];
            }
            unsigned own[4][2];
            #pragma unroll
            for (int g = 0; g < 4; g++) {
                own[g][0] = pack2h(pr[4 * g],     pr[4 * g + 1]);
                own[g][1] = pack2h(pr[4 * g + 2], pr[4 * g + 3]);
            }
            // targeted exchange: hi=0 needs partner g1,g3; hi=1 needs g0,g2
            unsigned X0 = hi ? own[0][0] : own[1][0];
            unsigned X1 = hi ? own[0][1] : own[1][1];
            unsigned Y0 = hi ? own[2][0] : own[3][0];
            unsigned Y1 = hi ? own[2][1] : own[3][1];
            const unsigned rX0 = __shfl_xor(X0, 32, 64);
            const unsigned rX1 = __shfl_xor(X1, 32, 64);
            const unsigned rY0 = __shfl_xor(Y0, 32, 64);
            const unsigned rY1 = __shfl_xor(Y1, 32, 64);

            union { unsigned u[4]; h8 h; } pa0, pa1;
            pa0.u[0] = hi ? rX0 : own[0][0];
            pa0.u[1] = hi ? rX1 : own[0][1];
            pa0.u[2] = hi ? own[1][0] : rX0;
            pa0.u[3] = hi ? own[1][1] : rX1;
            pa1.u[0] = hi ? rY0 : own[2][0];
            pa1.u[1] = hi ? rY1 : own[2][1];
            pa1.u[2] = hi ? own[3][0] : rY0;
            pa1.u[3] = hi ? own[3][1] : rY1;

            const int vc0 = st * 32 + hi * 8;
            h8 b00 = *(const h8*)&vb[rq * 72 + vc0];
            h8 b10 = *(const h8*)&vb[(32 + rq) * 72 + vc0];
            o0 = __builtin_amdgcn_mfma_f32_32x32x16_f16(pa0.h, b00, o0, 0, 0, 0);
            o1 = __builtin_amdgcn_mfma_f32_32x32x16_f16(pa0.h, b10, o1, 0, 0, 0);
            h8 b01 = *(const h8*)&vb[rq * 72 + vc0 + 16];
            h8 b11 = *(const h8*)&vb[(32 + rq) * 72 + vc0 + 16];
            o0 = __builtin_amdgcn_mfma_f32_32x32x16_f16(pa1.h, b01, o0, 0, 0, 0);
            o1 = __builtin_amdgcn_mfma_f32_32x32x16_f16(pa1.h, b11, o1, 0, 0, 0);
        }

        // write prefetched V into the other buffer (its readers finished at
        // the barrier ending superstep it-1); one barrier publishes it.
        if (more) {
            _Float16* wbuf = vtsm + (p ^ 1) * 9216;
            #pragma unroll
            for (int b2 = 0; b2 < 2; b2++)
                #pragma unroll
                for (int i = 0; i < 2; i++) {
                    const int flat = i * 2048 + tid8;
                    const int row = flat >> 6, col = flat & 63;
                    *(h8*)&wbuf[b2 * 4608 + row * 72 + col] = vpre[b2 * 2 + i];
                }
            #pragma unroll
            for (int st = 0; st < 2; st++)
                #pragma unroll
                for (int kf = 0; kf < 4; kf++)
                    kc[st][kf] = kpre[st][kf];
        }
        BAR();
    }

    // fold half-wave partner (hi split of s within this wave's chunk)
    lsum += __shfl_xor(lsum, 32, 64);

    // cross-pair combine: waves sw=1 hand off to sw=0 via LDS overlay
    float* comb = (float*)smem;                 // [2][32][64]
    float* lsp  = (float*)(smem + 36864);       // [2][32]
    float* invp = (float*)(smem + 37120);       // [2][32]

    if (wave >= 2) {
        float* c = comb + qs * 2048;
        #pragma unroll
        for (int r = 0; r < 16; r++) {
            const int row = (r & 3) + 8 * (r >> 2) + 4 * hi;
            c[row * 64 + rq]      = o0[r];
            c[row * 64 + 32 + rq] = o1[r];
        }
        if (hi == 0) lsp[qs * 32 + rq] = lsum;
    }
    BAR();
    if (wave < 2) {
        lsum += lsp[qs * 32 + rq];
        invp[qs * 32 + rq] = 1.0f / lsum;       // hi halves write same value
        asm volatile("s_waitcnt lgkmcnt(0)" ::: "memory");
        const int b = head >> 4, h = head & 15;
        const float* c = comb + qs * 2048;
        #pragma unroll
        for (int r = 0; r < 16; r++) {
            const int row = (r & 3) + 8 * (r >> 2) + 4 * hi;
            const float inv = invp[qs * 32 + row];
            const int ql = qw + row;
            const size_t base = (size_t)(ql * BB + b) * DD + h * DKK;
            oh[base + rq]      = (_Float16)((o0[r] + c[row * 64 + rq]) * inv);
            oh[base + 32 + rq] = (_Float16)((o1[r] + c[row * 64 + 32 + rq]) * inv);
        }
    }
}

// ---------------------------------------------------------------------------
// Kernel 3: output projection, m97 structure, 64x128 tiles (grid 512).
// ---------------------------------------------------------------------------
__global__ __launch_bounds__(256) void out_proj(
    const _Float16* __restrict__ oh, const _Float16* __restrict__ wo,
    const float* __restrict__ bo, float* __restrict__ out)
{
    __shared__ alignas(16) _Float16 a_sm[64 * 32];
    __shared__ alignas(16) _Float16 b_sm[128 * 32];
    const int tid = threadIdx.x, lane = tid & 63, wave = tid >> 6;
    const int wm = (wave & 1) * 32, wn = (wave >> 1) * 64;
    const int m0 = blockIdx.x * 64, n0 = blockIdx.y * 128;

    const int srow = tid >> 2;
    const int scol = (tid & 3) * 8;
    const int lds_base = wave * 512;

    f4 acc[2][4];
    #pragma unroll
    for (int i = 0; i < 2; i++)
        #pragma unroll
        for (int j = 0; j < 4; j++)
            #pragma unroll
            for (int r = 0; r < 4; r++) acc[i][j][r] = 0.f;

    const int fr = lane & 15;
    const int fk = (lane >> 4) * 8;

    for (int k0 = 0; k0 < DD; k0 += 32) {
        gload_lds16(oh + (size_t)(m0 + srow) * DD + k0 + scol,      &a_sm[lds_base]);
        gload_lds16(wo + (size_t)(n0 + srow) * DD + k0 + scol,      &b_sm[lds_base]);
        gload_lds16(wo + (size_t)(n0 + 64 + srow) * DD + k0 + scol, &b_sm[2048 + lds_base]);
        __syncthreads();
        h8 af[2], bfr[4];
        #pragma unroll
        for (int i = 0; i < 2; i++) af[i]  = *(const h8*)&a_sm[(wm + i * 16 + fr) * 32 + fk];
        #pragma unroll
        for (int j = 0; j < 4; j++) bfr[j] = *(const h8*)&b_sm[(wn + j * 16 + fr) * 32 + fk];
        #pragma unroll
        for (int i = 0; i < 2; i++)
            #pragma unroll
            for (int j = 0; j < 4; j++)
                acc[i][j] = __builtin_amdgcn_mfma_f32_16x16x32_f16(af[i], bfr[j], acc[i][j], 0, 0, 0);
        __syncthreads();
    }

    const int colc = lane & 15;
    const int rowb = (lane >> 4) * 4;
    #pragma unroll
    for (int i = 0; i < 2; i++) {
        #pragma unroll
        for (int j = 0; j < 4; j++) {
            const int nn = n0 + wn + j * 16 + colc;
            const float bval = bo[nn];
            #pragma unroll
            for (int reg = 0; reg < 4; reg++) {
                const int mm = m0 + wm + i * 16 + rowb + reg;
                out[(size_t)mm * DD + nn] = acc[i][j][reg] + bval;
            }
        }
    }
}

extern "C" void kernel_launch(void* const* d_in, const int* in_sizes, int n_in,
                              void* d_out, int out_size, void* d_ws, size_t ws_size,
                              hipStream_t stream) {
    const float* qin = (const float*)d_in[0];
    const float* kin = (const float*)d_in[1];
    const float* vin = (const float*)d_in[2];
    const float* wq  = (const float*)d_in[3];
    const float* bq  = (const float*)d_in[4];
    const float* wk  = (const float*)d_in[5];
    const float* bk  = (const float*)d_in[6];
    const float* wv  = (const float*)d_in[7];
    const float* bv  = (const float*)d_in[8];
    const float* wo  = (const float*)d_in[9];
    const float* bo  = (const float*)d_in[10];

    // ws layout (halves): qh,kh,vth,oh (4M each) | wqh,wkh,wvh,woh (1M each)
    //                     | xqh,xkh,xvh (4M each)  => 64 MB total
    const size_t seg = (size_t)32 * LL * DKK;  // 4,194,304
    _Float16* qh  = (_Float16*)d_ws;
    _Float16* kh  = qh + seg;
    _Float16* vth = kh + seg;
    _Float16* oh  = vth + seg;
    _Float16* wqh = oh + seg;
    _Float16* wkh = wqh + (size_t)DD * DD;
    _Float16* wvh = wkh + (size_t)DD * DD;
    _Float16* woh = wvh + (size_t)DD * DD;
    _Float16* xqh = woh + (size_t)DD * DD;
    _Float16* xkh = xqh + seg;
    _Float16* xvh = xkh + seg;

    hipLaunchKernelGGL(cvt_all, dim3(2048, 7), dim3(256), 0, stream,
                       qin, kin, vin, wq, wk, wv, wo,
                       xqh, xkh, xvh, wqh, wkh, wvh, woh);
    hipLaunchKernelGGL(qkv_proj, dim3(32, 8, 3), dim3(256), 0, stream,
                       xqh, xkh, xvh, wqh, bq, wkh, bk, wvh, bv, qh, kh, vth);
    hipLaunchKernelGGL(attn, dim3(32, 32), dim3(256), 0, stream, qh, kh, vth, oh);
    hipLaunchKernelGGL(out_proj, dim3(64, 8), dim3(256), 0, stream, oh, woh,
                       bo, (float*)d_out);
}